// Round 8
// baseline (299.109 us; speedup 1.0000x reference)
//
#include <hip/hip_runtime.h>

#define DEPTH 128
#define GPB 16   // graphs per block in the MLP kernel

typedef float f2 __attribute__((ext_vector_type(2)));
typedef float f4 __attribute__((ext_vector_type(4)));

// Kernel 1: segment boundary search. batch is sorted; start[g] = first index
// with batch[i] >= g, for g in [0, G].
__global__ void find_starts_kernel(const int* __restrict__ batch,
                                   int* __restrict__ start, int N, int G) {
    int g = blockIdx.x * blockDim.x + threadIdx.x;
    if (g > G) return;
    int lo = 0, hi = N;
    while (lo < hi) {
        int mid = (lo + hi) >> 1;
        if (batch[mid] < g) lo = mid + 1; else hi = mid;
    }
    start[g] = lo;
}

// Kernel 2: ONE WAVE PER GRAPH. A row is 128 f32 = 64 lanes x float2, so lane
// l owns dims (2l, 2l+1) across all rows of its graph: no LDS, no barriers,
// no cross-lane reduction anywhere. 8-deep unroll keeps 4 KB in flight/wave.
__global__ __launch_bounds__(256) void pool_kernel(
    const f2* __restrict__ x2, const int* __restrict__ start,
    float* __restrict__ pooled, int G)
{
    const int lane = threadIdx.x & 63;
    const int wid  = blockIdx.x * 4 + (threadIdx.x >> 6);   // wave id == graph id
    if (wid >= G) return;

    const int s0 = start[wid];
    const int s1 = start[wid + 1];

    f2 sum0 = (f2)(0.f);
    f2 sum1 = sum0, sum2 = sum0, sum3 = sum0;
    f2 sum4 = sum0, sum5 = sum0, sum6 = sum0, sum7 = sum0;
    f2 mx0 = (f2)(-INFINITY);
    f2 mx1 = mx0, mx2 = mx0, mx3 = mx0;
    f2 mx4 = mx0, mx5 = mx0, mx6 = mx0, mx7 = mx0;

#define ACC(v, s, m) do { \
        (s) += (v); \
        (m).x = fmaxf((m).x, (v).x); (m).y = fmaxf((m).y, (v).y); } while (0)

    int r = s0;
    for (; r + 7 < s1; r += 8) {
        // 8 independent loads issued back-to-back (row stride = 64 f2)
        f2 v0 = x2[(size_t)(r + 0) * 64 + lane];
        f2 v1 = x2[(size_t)(r + 1) * 64 + lane];
        f2 v2 = x2[(size_t)(r + 2) * 64 + lane];
        f2 v3 = x2[(size_t)(r + 3) * 64 + lane];
        f2 v4 = x2[(size_t)(r + 4) * 64 + lane];
        f2 v5 = x2[(size_t)(r + 5) * 64 + lane];
        f2 v6 = x2[(size_t)(r + 6) * 64 + lane];
        f2 v7 = x2[(size_t)(r + 7) * 64 + lane];
        ACC(v0, sum0, mx0); ACC(v1, sum1, mx1);
        ACC(v2, sum2, mx2); ACC(v3, sum3, mx3);
        ACC(v4, sum4, mx4); ACC(v5, sum5, mx5);
        ACC(v6, sum6, mx6); ACC(v7, sum7, mx7);
    }
    for (; r < s1; ++r) {
        f2 v = x2[(size_t)r * 64 + lane];
        ACC(v, sum0, mx0);
    }
#undef ACC

    // fold 8 accumulator pairs (register-only)
    sum0 += sum1; sum2 += sum3; sum4 += sum5; sum6 += sum7;
    sum0 += sum2; sum4 += sum6; sum0 += sum4;
    mx0.x = fmaxf(mx0.x, mx1.x); mx0.y = fmaxf(mx0.y, mx1.y);
    mx2.x = fmaxf(mx2.x, mx3.x); mx2.y = fmaxf(mx2.y, mx3.y);
    mx4.x = fmaxf(mx4.x, mx5.x); mx4.y = fmaxf(mx4.y, mx5.y);
    mx6.x = fmaxf(mx6.x, mx7.x); mx6.y = fmaxf(mx6.y, mx7.y);
    mx0.x = fmaxf(mx0.x, mx2.x); mx0.y = fmaxf(mx0.y, mx2.y);
    mx4.x = fmaxf(mx4.x, mx6.x); mx4.y = fmaxf(mx4.y, mx6.y);
    mx0.x = fmaxf(mx0.x, mx4.x); mx0.y = fmaxf(mx0.y, mx4.y);

    const int cnt = s1 - s0;
    const float inv = 1.0f / (float)(cnt > 1 ? cnt : 1);
    if (cnt == 0) mx0 = (f2)(0.f);
    f2 mean2 = sum0 * inv;

    f2* prow = reinterpret_cast<f2*>(pooled + (size_t)wid * 3 * DEPTH);
    prow[lane]       = mx0;    // max   [0:128)
    prow[64 + lane]  = mean2;  // mean  [128:256)
    prow[128 + lane] = sum0;   // sum   [256:384)
}

// Kernel 3: MLP over pooled features, GPB graphs per block (weights amortized).
__global__ __launch_bounds__(256) void mlp_kernel(
    const float* __restrict__ pooled,
    const float* __restrict__ W1, const float* __restrict__ b1,
    const float* __restrict__ W2, const float* __restrict__ b2,
    float* __restrict__ out, int G)
{
    __shared__ float h[GPB][3 * DEPTH];   // 24 KB
    __shared__ float a[GPB][DEPTH];       // 8 KB
    const int tid = threadIdx.x;
    const int g0  = blockIdx.x * GPB;

    {
        const f4* p4 = reinterpret_cast<const f4*>(pooled + (size_t)g0 * 3 * DEPTH);
        f4* h4 = reinterpret_cast<f4*>(&h[0][0]);
        const int total = GPB * 3 * DEPTH / 4;   // 1536
        for (int i = tid; i < total; i += 256) h4[i] = p4[i];
    }
    __syncthreads();

    const int j  = tid & 127;               // output dim
    const int gh = (tid >> 7) * (GPB / 2);  // 0 or 8

    float acc[GPB / 2];
    #pragma unroll
    for (int i = 0; i < GPB / 2; ++i) acc[i] = b1[j];
    {
        const f4* w1r = reinterpret_cast<const f4*>(W1 + (size_t)j * 3 * DEPTH);
        for (int k = 0; k < 3 * DEPTH / 4; ++k) {
            f4 w = w1r[k];
            #pragma unroll
            for (int i = 0; i < GPB / 2; ++i) {
                f4 hv = reinterpret_cast<const f4*>(h[gh + i])[k];  // LDS broadcast
                acc[i] += w.x * hv.x + w.y * hv.y + w.z * hv.z + w.w * hv.w;
            }
        }
    }
    #pragma unroll
    for (int i = 0; i < GPB / 2; ++i)
        a[gh + i][j] = (acc[i] > 0.f) ? acc[i] : 0.01f * acc[i];
    __syncthreads();

    #pragma unroll
    for (int i = 0; i < GPB / 2; ++i) acc[i] = b2[j];
    {
        const f4* w2r = reinterpret_cast<const f4*>(W2 + (size_t)j * DEPTH);
        for (int k = 0; k < DEPTH / 4; ++k) {
            f4 w = w2r[k];
            #pragma unroll
            for (int i = 0; i < GPB / 2; ++i) {
                f4 av = reinterpret_cast<const f4*>(a[gh + i])[k];  // LDS broadcast
                acc[i] += w.x * av.x + w.y * av.y + w.z * av.z + w.w * av.w;
            }
        }
    }
    #pragma unroll
    for (int i = 0; i < GPB / 2; ++i) {
        const int g = g0 + gh + i;
        if (g < G) out[(size_t)g * DEPTH + j] = acc[i];
    }
}

extern "C" void kernel_launch(void* const* d_in, const int* in_sizes, int n_in,
                              void* d_out, int out_size, void* d_ws, size_t ws_size,
                              hipStream_t stream) {
    const float* x     = (const float*)d_in[0];
    const int*   batch = (const int*)d_in[1];
    const float* W1 = (const float*)d_in[3];
    const float* b1 = (const float*)d_in[4];
    const float* W2 = (const float*)d_in[5];
    const float* b2 = (const float*)d_in[6];
    float* out = (float*)d_out;

    const int N = in_sizes[0] / DEPTH;   // 2,000,000 nodes
    const int G = out_size / DEPTH;      // 4096 graphs

    int*   start  = (int*)d_ws;                           // G+1 ints
    float* pooled = (float*)((char*)d_ws + 32768);        // G*384 f32, rewritten

    find_starts_kernel<<<(G + 256) / 256, 256, 0, stream>>>(batch, start, N, G);
    pool_kernel<<<(G + 3) / 4, 256, 0, stream>>>(
        (const f2*)x, start, pooled, G);
    mlp_kernel<<<(G + GPB - 1) / GPB, 256, 0, stream>>>(
        pooled, W1, b1, W2, b2, out, G);
}